// Round 7
// baseline (161.150 us; speedup 1.0000x reference)
//
#include <hip/hip_runtime.h>
#include <hip/hip_bf16.h>

#define D 128
#define MARGIN 0.5f
#define JW 256          // j-window per block (8 phases of 32)
#define NWIN 32         // n / JW i-side slab count
#define NBI 64          // i-blocks of 128 rows; transpose slab count

typedef __attribute__((ext_vector_type(8))) short bf16x8;
typedef __attribute__((ext_vector_type(4))) float f32x4;

// ---------------- prep: bf16 convert + sq + slab/out init ----------------
// grid n/4 blocks x 256 = 64n threads = exactly n*NBI -> g indexes pap2/pan2
__global__ void prep_kernel(const float* __restrict__ x,
                            float* __restrict__ sq,
                            __hip_bfloat16* __restrict__ xb,
                            float* __restrict__ pap, float* __restrict__ pan,
                            float* __restrict__ pap2, float* __restrict__ pan2,
                            float* __restrict__ out, int n) {
    int tid = threadIdx.x;
    int row = blockIdx.x * 4 + (tid >> 6);
    int lane = tid & 63;
    const float2* xr = (const float2*)(x + (size_t)row * D);
    float2 v = xr[lane];
    __hip_bfloat162 b2;
    b2.x = __float2bfloat16(v.x);
    b2.y = __float2bfloat16(v.y);
    ((__hip_bfloat162*)(xb + (size_t)row * D))[lane] = b2;
    float s = v.x * v.x + v.y * v.y;
    #pragma unroll
    for (int o = 32; o > 0; o >>= 1) s += __shfl_xor(s, o, 64);
    if (lane == 0) sq[row] = s;

    // slab init: unwritten (bi,by) triangle holes must be neutral.
    // ap-slabs: 0 (identity for max over relu'd values); an-slabs: +1e30.
    int g = blockIdx.x * 256 + tid;          // [0, 64n)
    pap2[g] = 0.0f;
    pan2[g] = 1e30f;
    if (g < n * NWIN) { pap[g] = 0.0f; pan[g] = 1e30f; }
    if (blockIdx.x == 0 && tid == 0) *out = 0.0f;
}

// ---------------- gram: symmetric triangle blocks, both-side update -------
// R6 lesson: gram (~33us) is insensitive to schedule restructuring (counted
// vmcnt, traffic halving, stagger all ~neutral; all pipes <25% util). So
// HALVE THE WORK: dist & mask are symmetric and max/min are IDEMPOTENT --
// compute each pair once, update row i AND row j; duplicate coverage near
// the diagonal is harmless. Triangle: blocks (bi 0..63, by >= bi/2), 1056
// half-size blocks (j-window 256, 8 phases) = 51.6% of the pair work, still
// 4 blocks/CU (R3 proved occupancy matters).
// Coverage: pair i<j -> block (i/128, j/256) valid since j/256 >= (i/128)/2.
// i-side: verified R2 core (lap/lan, 16-lane shfl reduce, slab pap[by]).
// j-side (transpose): same acc, u = fmaf(-2,acc,s_i); reduce over the
// wave's 32 i-rows via in-lane unroll + shfl_xor(16/32) across quads; merge
// into 4 per-lane owner regs with COMPILE-TIME indices (phases fully
// unrolled; R5's rule-#20 scratch bug avoided); cross-wave merge once per
// block via the retired LDS ring; slab pap2[bi] (unique writer per (bi,j)).
// Pipeline: 4-slot 8KB ring, counted s_waitcnt vmcnt(4), 1 barrier/phase,
// setprio on MFMA cluster, global_load_lds w=16, XOR swizzle on global src.
__launch_bounds__(256, 4)
__global__ void gram_kernel(const __hip_bfloat16* __restrict__ xb,
                            const float* __restrict__ sq,
                            const int* __restrict__ tgt,
                            float* __restrict__ pap,
                            float* __restrict__ pan,
                            float* __restrict__ pap2,
                            float* __restrict__ pan2, int n) {
    __shared__ __align__(16) __hip_bfloat16 Bs[4][32 * D];  // 4 x 8KB ring
    __shared__ float sqs[JW];
    __shared__ int   tgs[JW];

    const int tid  = threadIdx.x;
    const int wid  = tid >> 6;
    const int lane = tid & 63;
    const int quad = lane >> 4;
    const int l    = lane & 15;

    // bid -> (bi, by) triangle mapping (by >= bi/2); <=64 scalar iters
    int bi = 0, rem = blockIdx.x;
    while (rem >= NWIN - (bi >> 1)) { rem -= NWIN - (bi >> 1); ++bi; }
    const int by = (bi >> 1) + rem;

    const int i0 = bi * 128;
    const int j0 = by * JW;
    const int rowbase = i0 + wid * 32;

    // A fragments, register-resident: lane holds A[m=l][k=quad*8+r]
    bf16x8 afrag[2][4];
    {
        const __hip_bfloat16* abase = xb + (size_t)(rowbase + l) * D + quad * 8;
        #pragma unroll
        for (int mt = 0; mt < 2; ++mt)
            #pragma unroll
            for (int ks = 0; ks < 4; ++ks)
                afrag[mt][ks] = *(const bf16x8*)(abase + (size_t)mt * 16 * D + ks * 32);
    }

    int li[2][4];
    float siv[2][4];   // sq for this lane's acc rows (also reused at store)
    #pragma unroll
    for (int mt = 0; mt < 2; ++mt)
        #pragma unroll
        for (int reg = 0; reg < 4; ++reg) {
            int r = rowbase + mt * 16 + quad * 4 + reg;
            li[mt][reg]  = tgt[r];
            siv[mt][reg] = sq[r];
        }

    float lap[8], lan[8];
    #pragma unroll
    for (int k = 0; k < 8; ++k) { lap[k] = -1e30f; lan[k] = 1e30f; }
    float jpreg[4], jnreg[4];
    #pragma unroll
    for (int k = 0; k < 4; ++k) { jpreg[k] = -1e30f; jnreg[k] = 1e30f; }

    const char* xbb = (const char*)xb;

    #define PREF_HALF(h)                                                      \
        do {                                                                  \
            const int s_ = (h) & 3;                                           \
            _Pragma("unroll")                                                 \
            for (int i_ = 0; i_ < 2; ++i_) {                                  \
                int q_ = wid * 128 + i_ * 64 + lane;                          \
                int r_ = q_ >> 4;                                             \
                int c_ = (q_ & 15) ^ (r_ & 15);                               \
                const char* g_ = xbb + (size_t)(j0 + (h) * 32 + r_) * 256     \
                                     + (size_t)c_ * 16;                       \
                char* l_ = (char*)Bs + (size_t)s_ * 8192                      \
                         + (size_t)(wid * 128 + i_ * 64) * 16;                \
                __builtin_amdgcn_global_load_lds(                             \
                    (const __attribute__((address_space(1))) void*)g_,        \
                    (__attribute__((address_space(3))) void*)l_, 16, 0, 0);   \
            }                                                                 \
        } while (0)

    // COMP: i-side (t = s_j - 2acc -> lap/lan) + j-side (u = s_i - 2acc ->
    // cross-quad shfl reduce -> owner reg). (h,jt) compile-time everywhere.
    #define COMP_HALF(h)                                                      \
        do {                                                                  \
            const char* Bb_ = (const char*)Bs + (size_t)((h) & 3) * 8192;     \
            _Pragma("unroll")                                                 \
            for (int jt = 0; jt < 2; ++jt) {                                  \
                f32x4 acc0 = (f32x4){0.f, 0.f, 0.f, 0.f};                     \
                f32x4 acc1 = (f32x4){0.f, 0.f, 0.f, 0.f};                     \
                __builtin_amdgcn_s_setprio(1);                                \
                _Pragma("unroll")                                             \
                for (int ks = 0; ks < 4; ++ks) {                              \
                    int q = (jt * 16 + l) * 16 + ((ks * 4 + quad) ^ l);       \
                    bf16x8 bfr = *(const bf16x8*)(Bb_ + (size_t)q * 16);      \
                    acc0 = __builtin_amdgcn_mfma_f32_16x16x32_bf16(           \
                        afrag[0][ks], bfr, acc0, 0, 0, 0);                    \
                    acc1 = __builtin_amdgcn_mfma_f32_16x16x32_bf16(           \
                        afrag[1][ks], bfr, acc1, 0, 0, 0);                    \
                }                                                             \
                __builtin_amdgcn_s_setprio(0);                                \
                const int jb_ = (h) * 32 + jt * 16;                           \
                float sjc = sqs[jb_ + l];                                     \
                int   tjc = tgs[jb_ + l];                                     \
                float jp = -1e30f, jn = 1e30f;                                \
                _Pragma("unroll")                                             \
                for (int reg = 0; reg < 4; ++reg) {                           \
                    float a0 = acc0[reg], a1 = acc1[reg];                     \
                    float t0 = fmaf(-2.0f, a0, sjc);                          \
                    float t1 = fmaf(-2.0f, a1, sjc);                          \
                    float u0 = fmaf(-2.0f, a0, siv[0][reg]);                  \
                    float u1 = fmaf(-2.0f, a1, siv[1][reg]);                  \
                    bool s0 = (li[0][reg] == tjc);                            \
                    bool s1 = (li[1][reg] == tjc);                            \
                    lap[reg]     = fmaxf(lap[reg],     s0 ? t0 : -1e30f);     \
                    lan[reg]     = fminf(lan[reg],     s0 ? 1e30f : t0);      \
                    lap[4 + reg] = fmaxf(lap[4 + reg], s1 ? t1 : -1e30f);     \
                    lan[4 + reg] = fminf(lan[4 + reg], s1 ? 1e30f : t1);      \
                    jp = fmaxf(jp, s0 ? u0 : -1e30f);                         \
                    jp = fmaxf(jp, s1 ? u1 : -1e30f);                         \
                    jn = fminf(jn, s0 ? 1e30f : u0);                          \
                    jn = fminf(jn, s1 ? 1e30f : u1);                          \
                }                                                             \
                jp = fmaxf(jp, __shfl_xor(jp, 16, 64));                       \
                jp = fmaxf(jp, __shfl_xor(jp, 32, 64));                       \
                jn = fminf(jn, __shfl_xor(jn, 16, 64));                       \
                jn = fminf(jn, __shfl_xor(jn, 32, 64));                       \
                {                                                             \
                    const int cw = (((h) * 2 + jt) & 3);                      \
                    const int rw = (((h) * 2 + jt) >> 2);                     \
                    jpreg[rw] = (quad == cw) ? fmaxf(jpreg[rw], jp)           \
                                             : jpreg[rw];                     \
                    jnreg[rw] = (quad == cw) ? fminf(jnreg[rw], jn)           \
                                             : jnreg[rw];                     \
                }                                                             \
            }                                                                 \
        } while (0)

    // prologue: 3 tiles in flight + metadata staged
    PREF_HALF(0);
    PREF_HALF(1);
    PREF_HALF(2);
    sqs[tid] = sq[j0 + tid];
    tgs[tid] = tgt[j0 + tid];
    asm volatile("s_waitcnt lgkmcnt(0)" ::: "memory");

    // steady phases (counted vmcnt: oldest tile landed, 2 stay in flight)
    #pragma unroll
    for (int h = 0; h < 6; ++h) {
        asm volatile("s_waitcnt vmcnt(4)" ::: "memory");
        __builtin_amdgcn_s_barrier();
        asm volatile("" ::: "memory");
        if (h < 5) PREF_HALF(h + 3);
        COMP_HALF(h);
    }
    asm volatile("s_waitcnt vmcnt(2)" ::: "memory");
    __builtin_amdgcn_s_barrier();
    asm volatile("" ::: "memory");
    COMP_HALF(6);
    asm volatile("s_waitcnt vmcnt(0)" ::: "memory");
    __builtin_amdgcn_s_barrier();
    asm volatile("" ::: "memory");
    COMP_HALF(7);

    #undef PREF_HALF
    #undef COMP_HALF

    // i-side: reduce across 16 column-lanes, store to slab by
    #pragma unroll
    for (int mt = 0; mt < 2; ++mt)
        #pragma unroll
        for (int reg = 0; reg < 4; ++reg) {
            float p = lap[mt * 4 + reg], q = lan[mt * 4 + reg];
            #pragma unroll
            for (int o = 1; o < 16; o <<= 1) {
                p = fmaxf(p, __shfl_xor(p, o, 64));
                q = fminf(q, __shfl_xor(q, o, 64));
            }
            if (l == mt * 4 + reg) {
                int gi = rowbase + mt * 16 + quad * 4 + reg;
                float s = siv[mt][reg];
                pap[(size_t)by * n + gi] = fmaxf(s + p, 0.0f);
                pan[(size_t)by * n + gi] = fmaxf(s + q, 0.0f);
            }
        }

    // j-side: cross-wave merge via retired ring (reads drained by sync),
    // store to transpose slab bi (unique writer per (bi, j))
    __syncthreads();
    float* scr = (float*)Bs;
    #pragma unroll
    for (int r = 0; r < 4; ++r) {
        int w = (r * 4 + quad) * 16 + l;     // lane's owned window cols
        scr[wid * 256 + w]        = jpreg[r];
        scr[1024 + wid * 256 + w] = jnreg[r];
    }
    __syncthreads();
    {
        int w = tid;                          // 256 threads, 1 col each
        float p2 = fmaxf(fmaxf(scr[w], scr[256 + w]),
                         fmaxf(scr[512 + w], scr[768 + w]));
        float n2 = fminf(fminf(scr[1024 + w], scr[1280 + w]),
                         fminf(scr[1536 + w], scr[1792 + w]));
        float sj = sqs[w];
        pap2[(size_t)bi * n + j0 + w] = fmaxf(sj + p2, 0.0f);
        pan2[(size_t)bi * n + j0 + w] = fmaxf(sj + n2, 0.0f);
    }
}

// ---------------- final: reduce 32+64 slabs, sum relu(ap - an + margin) ---
__global__ void final_kernel(const float* __restrict__ pap,
                             const float* __restrict__ pan,
                             const float* __restrict__ pap2,
                             const float* __restrict__ pan2,
                             float* __restrict__ out, int n) {
    int i = blockIdx.x * blockDim.x + threadIdx.x;
    float p = pap[i], q = pan[i];
    #pragma unroll 4
    for (int s = 1; s < NWIN; ++s) {
        p = fmaxf(p, pap[(size_t)s * n + i]);
        q = fminf(q, pan[(size_t)s * n + i]);
    }
    #pragma unroll 4
    for (int b = 0; b < NBI; ++b) {
        p = fmaxf(p, pap2[(size_t)b * n + i]);
        q = fminf(q, pan2[(size_t)b * n + i]);
    }
    float v = fmaxf(p - q + MARGIN, 0.0f);
    #pragma unroll
    for (int o = 32; o > 0; o >>= 1) v += __shfl_xor(v, o, 64);
    __shared__ float ws[4];
    int lane = threadIdx.x & 63, w = threadIdx.x >> 6;
    if (lane == 0) ws[w] = v;
    __syncthreads();
    if (threadIdx.x == 0) atomicAdd(out, ws[0] + ws[1] + ws[2] + ws[3]);
}

extern "C" void kernel_launch(void* const* d_in, const int* in_sizes, int n_in,
                              void* d_out, int out_size, void* d_ws, size_t ws_size,
                              hipStream_t stream) {
    const float* x   = (const float*)d_in[0];
    const int*   tgt = (const int*)d_in[1];
    float* out = (float*)d_out;
    const int n = in_sizes[1];              // 8192

    // ws: sq | pap[NWIN*n] | pan[NWIN*n] | pap2[NBI*n] | pan2[NBI*n] | xb
    float* sq   = (float*)d_ws;
    float* pap  = sq + n;
    float* pan  = pap + (size_t)NWIN * n;
    float* pap2 = pan + (size_t)NWIN * n;
    float* pan2 = pap2 + (size_t)NBI * n;
    __hip_bfloat16* xb = (__hip_bfloat16*)(pan2 + (size_t)NBI * n);

    int nblk = 0;
    for (int b = 0; b < NBI; ++b) nblk += NWIN - (b >> 1);   // 1056

    prep_kernel<<<n / 4, 256, 0, stream>>>(x, sq, xb, pap, pan, pap2, pan2, out, n);
    gram_kernel<<<nblk, 256, 0, stream>>>(xb, sq, tgt, pap, pan, pap2, pan2, n);
    final_kernel<<<n / 256, 256, 0, stream>>>(pap, pan, pap2, pan2, out, n);
}

// Round 8
// 154.667 us; speedup vs baseline: 1.0419x; 1.0419x over previous
//
#include <hip/hip_runtime.h>
#include <hip/hip_bf16.h>

#define D 128
#define MARGIN 0.5f
#define JW 256          // j-window per block (8 phases of 32)
#define NWIN 32         // n / JW i-side slab count
#define NBI 64          // i-blocks of 128 rows; transpose slab count

typedef __attribute__((ext_vector_type(8))) short bf16x8;
typedef __attribute__((ext_vector_type(4))) float f32x4;

// ---------------- prep: bf16 convert + sq + slab/out init ----------------
// grid n/4 blocks x 256 = 64n threads = exactly n*NBI -> g indexes pap2/pan2
__global__ void prep_kernel(const float* __restrict__ x,
                            float* __restrict__ sq,
                            __hip_bfloat16* __restrict__ xb,
                            float* __restrict__ pap, float* __restrict__ pan,
                            float* __restrict__ pap2, float* __restrict__ pan2,
                            float* __restrict__ out, int n) {
    int tid = threadIdx.x;
    int row = blockIdx.x * 4 + (tid >> 6);
    int lane = tid & 63;
    const float2* xr = (const float2*)(x + (size_t)row * D);
    float2 v = xr[lane];
    __hip_bfloat162 b2;
    b2.x = __float2bfloat16(v.x);
    b2.y = __float2bfloat16(v.y);
    ((__hip_bfloat162*)(xb + (size_t)row * D))[lane] = b2;
    float s = v.x * v.x + v.y * v.y;
    #pragma unroll
    for (int o = 32; o > 0; o >>= 1) s += __shfl_xor(s, o, 64);
    if (lane == 0) sq[row] = s;

    // slab init: unwritten (bi,by) triangle holes must be neutral.
    int g = blockIdx.x * 256 + tid;          // [0, 64n)
    pap2[g] = 0.0f;
    pan2[g] = 1e30f;
    if (g < n * NWIN) { pap[g] = 0.0f; pan[g] = 1e30f; }
    if (blockIdx.x == 0 && tid == 0) *out = 0.0f;
}

// ---------------- gram: symmetric triangle, FULLY-STATIC phases (R8) ------
// R7 post-mortem: COMP_HALF(h) inside a runtime-h loop kept h runtime
// (asm-volatile barriers defeated #pragma unroll) -> jpreg[rw]/ring-slot
// runtime-indexed -> scratch (VGPR 64, WRITE_SIZE 132MB, gram 93us). Same
// triangle algorithm, but the 8 phases are MANUALLY EXPANDED with literal
// (h, jt) everywhere -- no runtime index touches any per-lane array.
// Algorithm: dist & mask symmetric, max/min idempotent -> compute each pair
// once, update row i AND row j. Blocks (bi 0..63, by >= bi/2) = 1056
// half-blocks (j-window 256) = 51.6% of pair work. Coverage: any (r,c) has
// c/256 >= r/256 (i-side of block r/128,c/256) or r/256 >= c/256 (j-side of
// block c/128,r/256); window-diagonal duplicates idempotent.
// Pipeline: 4-slot 8KB ring, counted s_waitcnt vmcnt (never 0 in steady
// state), 1 barrier/phase, setprio on MFMA, global_load_lds w=16, XOR
// swizzle on per-lane GLOBAL src (LDS dest wave-uniform + lane*16).
__launch_bounds__(256, 4)
__global__ void gram_kernel(const __hip_bfloat16* __restrict__ xb,
                            const float* __restrict__ sq,
                            const int* __restrict__ tgt,
                            float* __restrict__ pap,
                            float* __restrict__ pan,
                            float* __restrict__ pap2,
                            float* __restrict__ pan2, int n) {
    __shared__ __align__(16) __hip_bfloat16 Bs[4][32 * D];  // 4 x 8KB ring
    __shared__ float sqs[JW];
    __shared__ int   tgs[JW];

    const int tid  = threadIdx.x;
    const int wid  = tid >> 6;
    const int lane = tid & 63;
    const int quad = lane >> 4;
    const int l    = lane & 15;

    // bid -> (bi, by) triangle mapping (by >= bi/2); <=64 scalar iters
    int bi = 0, rem = blockIdx.x;
    while (rem >= NWIN - (bi >> 1)) { rem -= NWIN - (bi >> 1); ++bi; }
    const int by = (bi >> 1) + rem;

    const int i0 = bi * 128;
    const int j0 = by * JW;
    const int rowbase = i0 + wid * 32;

    // A fragments, register-resident: lane holds A[m=l][k=quad*8+r]
    bf16x8 afrag[2][4];
    {
        const __hip_bfloat16* abase = xb + (size_t)(rowbase + l) * D + quad * 8;
        #pragma unroll
        for (int mt = 0; mt < 2; ++mt)
            #pragma unroll
            for (int ks = 0; ks < 4; ++ks)
                afrag[mt][ks] = *(const bf16x8*)(abase + (size_t)mt * 16 * D + ks * 32);
    }

    int li[2][4];
    float siv[2][4];
    #pragma unroll
    for (int mt = 0; mt < 2; ++mt)
        #pragma unroll
        for (int reg = 0; reg < 4; ++reg) {
            int r = rowbase + mt * 16 + quad * 4 + reg;
            li[mt][reg]  = tgt[r];
            siv[mt][reg] = sq[r];
        }

    float lap[8], lan[8];
    #pragma unroll
    for (int k = 0; k < 8; ++k) { lap[k] = -1e30f; lan[k] = 1e30f; }
    float jpreg[4], jnreg[4];
    #pragma unroll
    for (int k = 0; k < 4; ++k) { jpreg[k] = -1e30f; jnreg[k] = 1e30f; }

    const char* xbb = (const char*)xb;

    #define PREF_HALF(h)                                                      \
        do {                                                                  \
            _Pragma("unroll")                                                 \
            for (int i_ = 0; i_ < 2; ++i_) {                                  \
                int q_ = wid * 128 + i_ * 64 + lane;                          \
                int r_ = q_ >> 4;                                             \
                int c_ = (q_ & 15) ^ (r_ & 15);                               \
                const char* g_ = xbb + (size_t)(j0 + (h) * 32 + r_) * 256     \
                                     + (size_t)c_ * 16;                       \
                char* l_ = (char*)Bs + (size_t)((h) & 3) * 8192               \
                         + (size_t)(wid * 128 + i_ * 64) * 16;                \
                __builtin_amdgcn_global_load_lds(                             \
                    (const __attribute__((address_space(1))) void*)g_,        \
                    (__attribute__((address_space(3))) void*)l_, 16, 0, 0);   \
            }                                                                 \
        } while (0)

    // ONE 16x16x32 j-tile: literal (h, jt) -> every array index literal.
    #define COMP_TILE(h, jt)                                                  \
        do {                                                                  \
            const char* Bb_ = (const char*)Bs + (size_t)((h) & 3) * 8192;     \
            f32x4 acc0 = (f32x4){0.f, 0.f, 0.f, 0.f};                         \
            f32x4 acc1 = (f32x4){0.f, 0.f, 0.f, 0.f};                         \
            __builtin_amdgcn_s_setprio(1);                                    \
            _Pragma("unroll")                                                 \
            for (int ks = 0; ks < 4; ++ks) {                                  \
                int q = ((jt) * 16 + l) * 16 + ((ks * 4 + quad) ^ l);         \
                bf16x8 bfr = *(const bf16x8*)(Bb_ + (size_t)q * 16);          \
                acc0 = __builtin_amdgcn_mfma_f32_16x16x32_bf16(               \
                    afrag[0][ks], bfr, acc0, 0, 0, 0);                        \
                acc1 = __builtin_amdgcn_mfma_f32_16x16x32_bf16(               \
                    afrag[1][ks], bfr, acc1, 0, 0, 0);                        \
            }                                                                 \
            __builtin_amdgcn_s_setprio(0);                                    \
            float sjc = sqs[(h) * 32 + (jt) * 16 + l];                        \
            int   tjc = tgs[(h) * 32 + (jt) * 16 + l];                        \
            float jp = -1e30f, jn = 1e30f;                                    \
            _Pragma("unroll")                                                 \
            for (int reg = 0; reg < 4; ++reg) {                               \
                float a0 = acc0[reg], a1 = acc1[reg];                         \
                float t0 = fmaf(-2.0f, a0, sjc);                              \
                float t1 = fmaf(-2.0f, a1, sjc);                              \
                float u0 = fmaf(-2.0f, a0, siv[0][reg]);                      \
                float u1 = fmaf(-2.0f, a1, siv[1][reg]);                      \
                bool s0 = (li[0][reg] == tjc);                                \
                bool s1 = (li[1][reg] == tjc);                                \
                lap[reg]     = fmaxf(lap[reg],     s0 ? t0 : -1e30f);         \
                lan[reg]     = fminf(lan[reg],     s0 ? 1e30f : t0);          \
                lap[4 + reg] = fmaxf(lap[4 + reg], s1 ? t1 : -1e30f);         \
                lan[4 + reg] = fminf(lan[4 + reg], s1 ? 1e30f : t1);          \
                jp = fmaxf(jp, s0 ? u0 : -1e30f);                             \
                jp = fmaxf(jp, s1 ? u1 : -1e30f);                             \
                jn = fminf(jn, s0 ? 1e30f : u0);                              \
                jn = fminf(jn, s1 ? 1e30f : u1);                              \
            }                                                                 \
            jp = fmaxf(jp, __shfl_xor(jp, 16, 64));                           \
            jp = fmaxf(jp, __shfl_xor(jp, 32, 64));                           \
            jn = fminf(jn, __shfl_xor(jn, 16, 64));                           \
            jn = fminf(jn, __shfl_xor(jn, 32, 64));                           \
            if (quad == (((h) * 2 + (jt)) & 3)) {                             \
                jpreg[((h) * 2 + (jt)) >> 2] =                                \
                    fmaxf(jpreg[((h) * 2 + (jt)) >> 2], jp);                  \
                jnreg[((h) * 2 + (jt)) >> 2] =                                \
                    fminf(jnreg[((h) * 2 + (jt)) >> 2], jn);                  \
            }                                                                 \
        } while (0)

    #define WAITBAR(N)                                                        \
        asm volatile("s_waitcnt vmcnt(" #N ")" ::: "memory");                 \
        __builtin_amdgcn_s_barrier();                                         \
        asm volatile("" ::: "memory")

    // prologue: 3 tiles in flight + metadata staged
    PREF_HALF(0);
    PREF_HALF(1);
    PREF_HALF(2);
    sqs[tid] = sq[j0 + tid];
    tgs[tid] = tgt[j0 + tid];
    asm volatile("s_waitcnt lgkmcnt(0)" ::: "memory");

    // 8 phases, fully static (2 glds/wave per tile; 3 tiles in flight)
    WAITBAR(4); PREF_HALF(3); COMP_TILE(0, 0); COMP_TILE(0, 1);
    WAITBAR(4); PREF_HALF(4); COMP_TILE(1, 0); COMP_TILE(1, 1);
    WAITBAR(4); PREF_HALF(5); COMP_TILE(2, 0); COMP_TILE(2, 1);
    WAITBAR(4); PREF_HALF(6); COMP_TILE(3, 0); COMP_TILE(3, 1);
    WAITBAR(4); PREF_HALF(7); COMP_TILE(4, 0); COMP_TILE(4, 1);
    WAITBAR(4);               COMP_TILE(5, 0); COMP_TILE(5, 1);
    WAITBAR(2);               COMP_TILE(6, 0); COMP_TILE(6, 1);
    WAITBAR(0);               COMP_TILE(7, 0); COMP_TILE(7, 1);

    #undef PREF_HALF
    #undef COMP_TILE
    #undef WAITBAR

    // i-side: reduce across 16 column-lanes, store to slab by
    #pragma unroll
    for (int mt = 0; mt < 2; ++mt)
        #pragma unroll
        for (int reg = 0; reg < 4; ++reg) {
            float p = lap[mt * 4 + reg], q = lan[mt * 4 + reg];
            #pragma unroll
            for (int o = 1; o < 16; o <<= 1) {
                p = fmaxf(p, __shfl_xor(p, o, 64));
                q = fminf(q, __shfl_xor(q, o, 64));
            }
            if (l == mt * 4 + reg) {
                int gi = rowbase + mt * 16 + quad * 4 + reg;
                float s = siv[mt][reg];
                pap[(size_t)by * n + gi] = fmaxf(s + p, 0.0f);
                pan[(size_t)by * n + gi] = fmaxf(s + q, 0.0f);
            }
        }

    // j-side: cross-wave merge via retired ring (reads drained by sync),
    // store to transpose slab bi (unique writer per (bi, j))
    __syncthreads();
    float* scr = (float*)Bs;
    #pragma unroll
    for (int r = 0; r < 4; ++r) {
        int w = (r * 4 + quad) * 16 + l;     // lane's owned window cols
        scr[wid * 256 + w]        = jpreg[r];
        scr[1024 + wid * 256 + w] = jnreg[r];
    }
    __syncthreads();
    {
        int w = tid;                          // 256 threads, 1 col each
        float p2 = fmaxf(fmaxf(scr[w], scr[256 + w]),
                         fmaxf(scr[512 + w], scr[768 + w]));
        float n2 = fminf(fminf(scr[1024 + w], scr[1280 + w]),
                         fminf(scr[1536 + w], scr[1792 + w]));
        float sj = sqs[w];
        pap2[(size_t)bi * n + j0 + w] = fmaxf(sj + p2, 0.0f);
        pan2[(size_t)bi * n + j0 + w] = fmaxf(sj + n2, 0.0f);
    }
}

// ---------------- final: reduce 32+64 slabs, sum relu(ap - an + margin) ---
__global__ void final_kernel(const float* __restrict__ pap,
                             const float* __restrict__ pan,
                             const float* __restrict__ pap2,
                             const float* __restrict__ pan2,
                             float* __restrict__ out, int n) {
    int i = blockIdx.x * blockDim.x + threadIdx.x;
    float p = pap[i], q = pan[i];
    #pragma unroll 4
    for (int s = 1; s < NWIN; ++s) {
        p = fmaxf(p, pap[(size_t)s * n + i]);
        q = fminf(q, pan[(size_t)s * n + i]);
    }
    #pragma unroll 4
    for (int b = 0; b < NBI; ++b) {
        p = fmaxf(p, pap2[(size_t)b * n + i]);
        q = fminf(q, pan2[(size_t)b * n + i]);
    }
    float v = fmaxf(p - q + MARGIN, 0.0f);
    #pragma unroll
    for (int o = 32; o > 0; o >>= 1) v += __shfl_xor(v, o, 64);
    __shared__ float ws[4];
    int lane = threadIdx.x & 63, w = threadIdx.x >> 6;
    if (lane == 0) ws[w] = v;
    __syncthreads();
    if (threadIdx.x == 0) atomicAdd(out, ws[0] + ws[1] + ws[2] + ws[3]);
}

extern "C" void kernel_launch(void* const* d_in, const int* in_sizes, int n_in,
                              void* d_out, int out_size, void* d_ws, size_t ws_size,
                              hipStream_t stream) {
    const float* x   = (const float*)d_in[0];
    const int*   tgt = (const int*)d_in[1];
    float* out = (float*)d_out;
    const int n = in_sizes[1];              // 8192

    // ws: sq | pap[NWIN*n] | pan[NWIN*n] | pap2[NBI*n] | pan2[NBI*n] | xb
    float* sq   = (float*)d_ws;
    float* pap  = sq + n;
    float* pan  = pap + (size_t)NWIN * n;
    float* pap2 = pan + (size_t)NWIN * n;
    float* pan2 = pap2 + (size_t)NBI * n;
    __hip_bfloat16* xb = (__hip_bfloat16*)(pan2 + (size_t)NBI * n);

    int nblk = 0;
    for (int b = 0; b < NBI; ++b) nblk += NWIN - (b >> 1);   // 1056

    prep_kernel<<<n / 4, 256, 0, stream>>>(x, sq, xb, pap, pan, pap2, pan2, out, n);
    gram_kernel<<<nblk, 256, 0, stream>>>(xb, sq, tgt, pap, pan, pap2, pan2, n);
    final_kernel<<<n / 256, 256, 0, stream>>>(pap, pan, pap2, pan2, out, n);
}